// Round 7
// baseline (186.650 us; speedup 1.0000x reference)
//
#include <hip/hip_runtime.h>
#include <hip/hip_bf16.h>
#include <stdint.h>

// Problem constants
#define NROWS 4096
#define NCLS  97
#define EMB   768
#define KTOT  49152                 // EMB * 64
#define OUT_ELEMS (NROWS * NCLS)    // 397312

typedef __attribute__((ext_vector_type(8)))  short short8;
typedef __attribute__((ext_vector_type(4)))  float floatx4;
typedef __bf16 bf16x2 __attribute__((ext_vector_type(2)));
typedef __bf16 bf16x8 __attribute__((ext_vector_type(8)));

__device__ __forceinline__ uint32_t pkmul(uint32_t a, uint32_t b) {
  bf16x2 x = __builtin_bit_cast(bf16x2, a);
  bf16x2 y = __builtin_bit_cast(bf16x2, b);
  bf16x2 r = x * y;
  return __builtin_bit_cast(uint32_t, r);
}

__device__ __forceinline__ uint4 cvt8(float4 a, float4 b) {
  bf16x8 v;
  v[0] = (__bf16)a.x; v[1] = (__bf16)a.y; v[2] = (__bf16)a.z; v[3] = (__bf16)a.w;
  v[4] = (__bf16)b.x; v[5] = (__bf16)b.y; v[6] = (__bf16)b.z; v[7] = (__bf16)b.w;
  return __builtin_bit_cast(uint4, v);
}

// Fused on-the-fly-A GEMM over kappa: logits[n,c] = sum_k A[n,k]*W[c,k].
// A[n, kb*4096 + i*64 + j] = b1[n,kb,i] * b2[n,kb,j]  (built in registers).
// Inputs read as f32 directly; converted to bf16 in registers.
// OUTPUT IS FLOAT32 (reference returns f32) — R7 fix.
//
// MFMA 16x16x32 bf16 — HW-verified triple (m89/m91/m120):
//   A: lane l holds A[m=l&15][k=(l>>4)*8+j]; B (W row-major): W[c=l&15][k=(l>>4)*8+j]
//   D: lane l, reg r: col(c)=l&15, row(n)=(l>>4)*4+r
//
// Grid: (32 row-tiles, KS). Block: 256. WG tile 128 rows x 128 cols.
__global__ __launch_bounds__(256, 2)
void bilinear_main(const float* __restrict__ b1g,
                   const float* __restrict__ b2g,
                   const float* __restrict__ Wg,
                   const float* __restrict__ biasg,
                   float* __restrict__ P,
                   float* __restrict__ outd,
                   int klen)
{
  __shared__ uint4 smem[1152];   // 128 rows x (8 chunks + 1 pad): 18 KB, no swizzle
  const int tid  = threadIdx.x;
  const int w    = tid >> 6;
  const int l    = tid & 63;
  const int l15  = l & 15;
  const int quad = l >> 4;
  const int mhalf = w & 1;
  const int chalf = w >> 1;
  const int bm = blockIdx.x;
  const int k0 = blockIdx.y * klen;

  // Staging: 1024 chunks of 8 elems; chunk s: row c=s>>3, slot g=s&7 at smem[c*9+g].
  const float* wsrcf[4];
  int sidx[4];
#pragma unroll
  for (int r = 0; r < 4; ++r) {
    int s  = r * 256 + tid;
    int c  = s >> 3;
    int g  = s & 7;
    int cc = c > 96 ? 96 : c;        // padded classes duplicate row 96 (never stored)
    wsrcf[r] = Wg + (size_t)cc * KTOT + g * 8;
    sidx[r]  = c * 9 + g;
  }

  int nrow[4];
#pragma unroll
  for (int rt = 0; rt < 4; ++rt) nrow[rt] = bm * 128 + mhalf * 64 + rt * 16 + l15;
  int ccol[4];
#pragma unroll
  for (int ct = 0; ct < 4; ++ct) ccol[ct] = chalf * 64 + ct * 16 + l15;
  int rbase[4];
#pragma unroll
  for (int ct = 0; ct < 4; ++ct) rbase[ct] = ccol[ct] * 9;

  floatx4 acc[4][4];
#pragma unroll
  for (int rt = 0; rt < 4; ++rt)
#pragma unroll
    for (int ct = 0; ct < 4; ++ct)
      acc[rt][ct] = floatx4{0.f, 0.f, 0.f, 0.f};

  uint4  b2c[4][2];     // bf16 b2[nrow[rt], kblk, kh*32+quad*8 .. +7]
  float4 b1f[4][2];     // f32 b1[nrow[rt], kblk, i0 .. i0+7]
  int cur_k = -1;

  for (int kap = k0; kap < k0 + klen; kap += 512) {   // 8 windows of 64 kappa
    const int kblk = kap >> 12;
    const int i0   = (kap >> 6) & 63;
    if (kblk != cur_k) {
      cur_k = kblk;
#pragma unroll
      for (int rt = 0; rt < 4; ++rt)
#pragma unroll
        for (int kh = 0; kh < 2; ++kh) {
          const float* p = b2g + (size_t)nrow[rt] * EMB + kblk * 64 + kh * 32 + quad * 8;
          b2c[rt][kh] = cvt8(((const float4*)p)[0], ((const float4*)p)[1]);
        }
    }
#pragma unroll
    for (int rt = 0; rt < 4; ++rt) {
      const float* p = b1g + (size_t)nrow[rt] * EMB + kblk * 64 + i0;
      b1f[rt][0] = ((const float4*)p)[0];
      b1f[rt][1] = ((const float4*)p)[1];
    }

#pragma unroll
    for (int ii = 0; ii < 8; ++ii) {
      const int kr = kap + ii * 64;   // window base in kappa space

      // Stage W window: f32 loads -> bf16 convert (overlaps prior MFMAs)
      uint4 stg[4];
#pragma unroll
      for (int r = 0; r < 4; ++r) {
        const float* p = wsrcf[r] + kr;
        stg[r] = cvt8(((const float4*)p)[0], ((const float4*)p)[1]);
      }

      // A fragments: afr[rt][kh] elem j = bf16(b1[n,i0+ii]) * bf16(b2[n, kh*32+quad*8+j])
      uint4 afr[4][2];
#pragma unroll
      for (int rt = 0; rt < 4; ++rt) {
        float bs = ((const float*)&b1f[rt][ii >> 2])[ii & 3];
        __bf16 hb = (__bf16)bs;
        uint32_t hx = (uint32_t)__builtin_bit_cast(uint16_t, hb);
        uint32_t s2 = hx | (hx << 16);
#pragma unroll
        for (int kh = 0; kh < 2; ++kh) {
          afr[rt][kh].x = pkmul(s2, b2c[rt][kh].x);
          afr[rt][kh].y = pkmul(s2, b2c[rt][kh].y);
          afr[rt][kh].z = pkmul(s2, b2c[rt][kh].z);
          afr[rt][kh].w = pkmul(s2, b2c[rt][kh].w);
        }
      }

      __syncthreads();                 // prior step's LDS reads done
#pragma unroll
      for (int r = 0; r < 4; ++r)
        smem[sidx[r]] = stg[r];        // ds_write_b128
      __syncthreads();                 // tile visible

#pragma unroll
      for (int kh = 0; kh < 2; ++kh) {
        short8 wf[4];
#pragma unroll
        for (int ct = 0; ct < 4; ++ct)
          wf[ct] = __builtin_bit_cast(short8, smem[rbase[ct] + kh * 4 + quad]);
#pragma unroll
        for (int rt = 0; rt < 4; ++rt) {
          short8 af = __builtin_bit_cast(short8, afr[rt][kh]);
#pragma unroll
          for (int ct = 0; ct < 4; ++ct)
            acc[rt][ct] = __builtin_amdgcn_mfma_f32_16x16x32_bf16(
                              af, wf[ct], acc[rt][ct], 0, 0, 0);
        }
      }
    }
  }

  // Epilogue. D: col(c)=l15, row(n)=quad*4+r within each 16x16 tile.
  if (P) {
    float* Pb = P + (size_t)blockIdx.y * OUT_ELEMS;
#pragma unroll
    for (int rt = 0; rt < 4; ++rt)
#pragma unroll
      for (int ct = 0; ct < 4; ++ct) {
        const int c = ccol[ct];
        if (c < NCLS) {
#pragma unroll
          for (int r = 0; r < 4; ++r) {
            const int row = bm * 128 + mhalf * 64 + rt * 16 + quad * 4 + r;
            Pb[(size_t)row * NCLS + c] = acc[rt][ct][r];
          }
        }
      }
  } else {
#pragma unroll
    for (int rt = 0; rt < 4; ++rt)
#pragma unroll
      for (int ct = 0; ct < 4; ++ct) {
        const int c = ccol[ct];
        if (c < NCLS) {
          const float bv = biasg[c];
#pragma unroll
          for (int r = 0; r < 4; ++r) {
            const int row = bm * 128 + mhalf * 64 + rt * 16 + quad * 4 + r;
            outd[(size_t)row * NCLS + c] = acc[rt][ct][r] + bv;   // f32 store
          }
        }
      }
  }
}

// Sum KS partial slices + f32 bias -> f32 output.
__global__ void reduce_bias(const float* __restrict__ P,
                            const float* __restrict__ biasg,
                            float* __restrict__ out, int KS)
{
  int idx = blockIdx.x * blockDim.x + threadIdx.x;
  if (idx >= OUT_ELEMS) return;
  int c = idx % NCLS;
  float s = biasg[c];
  for (int t = 0; t < KS; ++t) s += P[(size_t)t * OUT_ELEMS + idx];
  out[idx] = s;
}

extern "C" void kernel_launch(void* const* d_in, const int* in_sizes, int n_in,
                              void* d_out, int out_size, void* d_ws, size_t ws_size,
                              hipStream_t stream) {
  const float* b1f = (const float*)d_in[0];   // head_embeddings [4096,768] f32
  const float* b2f = (const float*)d_in[1];   // tail_embeddings [4096,768] f32
  const float* Wf  = (const float*)d_in[2];   // W [97, 49152] f32
  const float* bbf = (const float*)d_in[3];   // b [97] f32
  float* out = (float*)d_out;                 // f32 output (reference dtype)

  const size_t slice_bytes = (size_t)OUT_ELEMS * 4;   // 1,589,248
  // klen = KTOT/KS must be a multiple of 512: all candidates below qualify.
  static const int cands[] = {16, 12, 8, 6, 4, 3, 2, 1};
  int KS = 0;
  for (int i = 0; i < 8; ++i)
    if ((size_t)cands[i] * slice_bytes <= ws_size) { KS = cands[i]; break; }

  if (KS == 0) {
    // no usable workspace: single-pass, direct f32 output with bias
    bilinear_main<<<dim3(32, 1), 256, 0, stream>>>(b1f, b2f, Wf, bbf,
                                                   nullptr, out, KTOT);
  } else {
    float* P = (float*)d_ws;
    bilinear_main<<<dim3(32, KS), 256, 0, stream>>>(b1f, b2f, Wf, bbf,
                                                    P, nullptr, KTOT / KS);
    reduce_bias<<<(OUT_ELEMS + 255) / 256, 256, 0, stream>>>(P, bbf, out, KS);
  }
}